// Round 1
// baseline (3889.469 us; speedup 1.0000x reference)
//
#include <hip/hip_runtime.h>

#define HEADS 4

__device__ __forceinline__ unsigned enc_f(float f) {
    unsigned u = __float_as_uint(f);
    return (u & 0x80000000u) ? ~u : (u | 0x80000000u);
}
__device__ __forceinline__ float dec_f(unsigned u) {
    return (u & 0x80000000u) ? __uint_as_float(u & 0x7FFFFFFFu)
                             : __uint_as_float(~u);
}

// ---------------- GEMM: C[M,Ncols] = A[M,K] @ B[K,Ncols] ----------------
// BM=128, BN=32, BK=32, 256 threads, 4x4 micro-tile per thread.
__global__ __launch_bounds__(256)
void gemm_k(const float* __restrict__ A, const float* __restrict__ B,
            float* __restrict__ C, int M, int K, int Ncols) {
    constexpr int BM = 128, BN = 32, BK = 32;
    __shared__ float As[BK][BM];
    __shared__ float Bs[BK][BN];
    const int m0 = blockIdx.x * BM;
    const int n0 = blockIdx.y * BN;
    const int tid = threadIdx.x;
    const int ty = tid >> 3;  // 0..31 row group
    const int tx = tid & 7;   // 0..7  col group
    float acc[4][4] = {};
    for (int kt = 0; kt < K; kt += BK) {
        // stage A tile (128 rows x 32 k), transposed into As[k][m]
        #pragma unroll
        for (int it = 0; it < 4; ++it) {
            int i = tid + 256 * it;           // float4 slot 0..1023
            int row = i >> 3;
            int kc = (i & 7) * 4;
            int grow = m0 + row;
            float4 v = make_float4(0.f, 0.f, 0.f, 0.f);
            if (grow < M)
                v = *(const float4*)&A[(size_t)grow * K + kt + kc];
            As[kc + 0][row] = v.x;
            As[kc + 1][row] = v.y;
            As[kc + 2][row] = v.z;
            As[kc + 3][row] = v.w;
        }
        // stage B tile (32 k x 32 n)
        {
            int kr = tid >> 3;
            int nc = (tid & 7) * 4;
            *(float4*)&Bs[kr][nc] =
                *(const float4*)&B[(size_t)(kt + kr) * Ncols + n0 + nc];
        }
        __syncthreads();
        #pragma unroll
        for (int k = 0; k < BK; ++k) {
            float4 av = *(const float4*)&As[k][ty * 4];
            float4 bv = *(const float4*)&Bs[k][tx * 4];
            float a[4] = {av.x, av.y, av.z, av.w};
            float b[4] = {bv.x, bv.y, bv.z, bv.w};
            #pragma unroll
            for (int i = 0; i < 4; ++i)
                #pragma unroll
                for (int j = 0; j < 4; ++j)
                    acc[i][j] += a[i] * b[j];
        }
        __syncthreads();
    }
    #pragma unroll
    for (int i = 0; i < 4; ++i) {
        int grow = m0 + ty * 4 + i;
        if (grow < M) {
            float4 v = make_float4(acc[i][0], acc[i][1], acc[i][2], acc[i][3]);
            *(float4*)&C[(size_t)grow * Ncols + n0 + tx * 4] = v;
        }
    }
}

// ---------------- per-node alpha + sigmoid ----------------
__global__ __launch_bounds__(256)
void alpha_k(const float* __restrict__ xh, const float* __restrict__ attq,
             float* __restrict__ sa, int n, int C, int HC) {
    const int t = blockIdx.x * blockDim.x + threadIdx.x;
    if (t >= n * HEADS) return;
    const int nd = t >> 2, h = t & 3;
    const float* xr = &xh[(size_t)nd * HC + h * C];
    const float* q = &attq[h * C];
    float s = 0.f;
    for (int c = 0; c < C; c += 4) {
        float4 a = *(const float4*)&xr[c];
        float4 b = *(const float4*)&q[c];
        s += a.x * b.x + a.y * b.y + a.z * b.z + a.w * b.w;
    }
    sa[t] = 1.0f / (1.0f + expf(-s));
}

__global__ __launch_bounds__(256)
void init_m_k(unsigned* __restrict__ mb, int ntot) {
    const int t = blockIdx.x * blockDim.x + threadIdx.x;
    if (t < ntot) mb[t] = 0x007FFFFFu;  // enc(-inf)
}

// ---------------- per-(edge,head) logits + segment max ----------------
template <int C>
__global__ __launch_bounds__(256)
void edge_logit_k(const int* __restrict__ src, const int* __restrict__ dst,
                  const float* __restrict__ xh, const float* __restrict__ sa,
                  const float* __restrict__ attv, float* __restrict__ exb,
                  unsigned* __restrict__ mb, int E) {
    constexpr int HC = 4 * C;
    __shared__ float av[HC];
    for (int i = threadIdx.x; i < HC; i += blockDim.x) av[i] = attv[i];
    __syncthreads();
    const int t = blockIdx.x * blockDim.x + threadIdx.x;
    if (t >= E * HEADS) return;
    const int e = t >> 2, h = t & 3;
    const int si = src[e], di = dst[e];
    const float sas = sa[si * 4 + h], sad = sa[di * 4 + h];
    const float wa = 1.0f - fabsf(sad - sas);
    const float* xs = &xh[(size_t)si * HC + h * C];
    const float* xd = &xh[(size_t)di * HC + h * C];
    float wb = 0.f;
    #pragma unroll
    for (int c = 0; c < C; c += 4) {
        float4 a = *(const float4*)&xs[c];
        float4 b = *(const float4*)&xd[c];
        float v0 = a.x + b.x; v0 = v0 > 0.f ? v0 : 0.01f * v0;
        float v1 = a.y + b.y; v1 = v1 > 0.f ? v1 : 0.01f * v1;
        float v2 = a.z + b.z; v2 = v2 > 0.f ? v2 : 0.01f * v2;
        float v3 = a.w + b.w; v3 = v3 > 0.f ? v3 : 0.01f * v3;
        wb += av[h * C + c] * v0 + av[h * C + c + 1] * v1 +
              av[h * C + c + 2] * v2 + av[h * C + c + 3] * v3;
    }
    const float el = wa * wb;
    exb[t] = el;
    atomicMax(&mb[di * 4 + h], enc_f(el));
}

// ---------------- exp + segment sum ----------------
__global__ __launch_bounds__(256)
void edge_exp_k(const int* __restrict__ dst, const unsigned* __restrict__ mb,
                float* __restrict__ exb, float* __restrict__ sb, int E) {
    const int t = blockIdx.x * blockDim.x + threadIdx.x;
    if (t >= E * HEADS) return;
    const int e = t >> 2, h = t & 3;
    const int di = dst[e];
    const float ex = expf(exb[t] - dec_f(mb[di * 4 + h]));
    exb[t] = ex;
    atomicAdd(&sb[di * 4 + h], ex);
}

// ---------------- weighted scatter-sum ----------------
// blockDim = 8*C, 8 edges per block, each thread does one float4 chunk.
template <int C>
__global__ void edge_scatter_k(const int* __restrict__ src, const int* __restrict__ dst,
                               const float* __restrict__ xh, const float* __restrict__ exb,
                               const float* __restrict__ sb, float* __restrict__ outb,
                               int E) {
    constexpr int HC = 4 * C;
    const int e_local = threadIdx.x / C;
    const int c4 = threadIdx.x % C;
    const int e = blockIdx.x * 8 + e_local;
    if (e >= E) return;
    const int h = (c4 * 4) / C;
    const int si = src[e], di = dst[e];
    const float w = exb[e * 4 + h] / (sb[di * 4 + h] + 1e-16f);
    const float4 v = *(const float4*)&xh[(size_t)si * HC + c4 * 4];
    float* o = outb + (size_t)di * HC + c4 * 4;
    atomicAdd(o + 0, v.x * w);
    atomicAdd(o + 1, v.y * w);
    atomicAdd(o + 2, v.z * w);
    atomicAdd(o + 3, v.w * w);
}

// ---------------- bias + ELU (layer-1 epilogue, in place) ----------------
__global__ __launch_bounds__(256)
void epi1_k(float* __restrict__ a, const float* __restrict__ bias, int ntot) {
    const int t = blockIdx.x * blockDim.x + threadIdx.x;
    if (t >= ntot) return;
    float v = a[t] + bias[t & 127];
    a[t] = v > 0.f ? v : expf(v) - 1.0f;
}

// ---------------- head-mean + bias2 -> d_out ----------------
__global__ __launch_bounds__(256)
void final_k(const float* __restrict__ acc, const float* __restrict__ bias2,
             float* __restrict__ outp, int n) {
    const int t = blockIdx.x * blockDim.x + threadIdx.x;
    if (t >= n * 40) return;
    const int nd = t / 40, c = t % 40;
    const float* r = &acc[(size_t)nd * 160];
    outp[t] = 0.25f * (r[c] + r[c + 40] + r[c + 80] + r[c + 120]) + bias2[c];
}

extern "C" void kernel_launch(void* const* d_in, const int* in_sizes, int n_in,
                              void* d_out, int out_size, void* d_ws, size_t ws_size,
                              hipStream_t stream) {
    const float* x      = (const float*)d_in[0];
    const int*   src    = (const int*)d_in[1];
    const int*   dst    = (const int*)d_in[2];
    const float* lin1   = (const float*)d_in[3];
    const float* att_q1 = (const float*)d_in[4];
    const float* att_v1 = (const float*)d_in[5];
    const float* bias1  = (const float*)d_in[6];
    const float* lin2   = (const float*)d_in[7];
    const float* att_q2 = (const float*)d_in[8];
    const float* att_v2 = (const float*)d_in[9];
    const float* bias2  = (const float*)d_in[10];
    float* outp = (float*)d_out;

    const int n = in_sizes[0] / 256;
    const int E = in_sizes[1];
    const int nh = n * HEADS;

    float* ws = (float*)d_ws;
    size_t o = 0;
    float*    xh  = ws + o; o += (size_t)n * 160;
    float*    accb = ws + o; o += (size_t)n * 160;
    float*    sa  = ws + o; o += (size_t)nh;
    unsigned* mb  = (unsigned*)(ws + o); o += (size_t)nh;
    float*    sb  = ws + o; o += (size_t)nh;
    float*    exb = ws + o; o += (size_t)E * HEADS;

    dim3 blk(256);

    // ================= layer 1: C=32, HC=128, K=256 =================
    gemm_k<<<dim3((n + 127) / 128, 128 / 32), blk, 0, stream>>>(x, lin1, xh, n, 256, 128);
    alpha_k<<<(nh + 255) / 256, blk, 0, stream>>>(xh, att_q1, sa, n, 32, 128);
    init_m_k<<<(nh + 255) / 256, blk, 0, stream>>>(mb, nh);
    hipMemsetAsync(sb, 0, (size_t)nh * 4, stream);
    hipMemsetAsync(accb, 0, (size_t)n * 128 * 4, stream);
    edge_logit_k<32><<<(E * HEADS + 255) / 256, blk, 0, stream>>>(src, dst, xh, sa, att_v1, exb, mb, E);
    edge_exp_k<<<(E * HEADS + 255) / 256, blk, 0, stream>>>(dst, mb, exb, sb, E);
    edge_scatter_k<32><<<(E + 7) / 8, dim3(256), 0, stream>>>(src, dst, xh, exb, sb, accb, E);
    epi1_k<<<(n * 128 + 255) / 256, blk, 0, stream>>>(accb, bias1, n * 128);

    // ================= layer 2: C=40, HC=160, K=128 =================
    gemm_k<<<dim3((n + 127) / 128, 160 / 32), blk, 0, stream>>>(accb, lin2, xh, n, 128, 160);
    alpha_k<<<(nh + 255) / 256, blk, 0, stream>>>(xh, att_q2, sa, n, 40, 160);
    init_m_k<<<(nh + 255) / 256, blk, 0, stream>>>(mb, nh);
    hipMemsetAsync(sb, 0, (size_t)nh * 4, stream);
    hipMemsetAsync(accb, 0, (size_t)n * 160 * 4, stream);
    edge_logit_k<40><<<(E * HEADS + 255) / 256, blk, 0, stream>>>(src, dst, xh, sa, att_v2, exb, mb, E);
    edge_exp_k<<<(E * HEADS + 255) / 256, blk, 0, stream>>>(dst, mb, exb, sb, E);
    edge_scatter_k<40><<<(E + 7) / 8, dim3(320), 0, stream>>>(src, dst, xh, exb, sb, accb, E);
    final_k<<<(n * 40 + 255) / 256, blk, 0, stream>>>(accb, bias2, outp, n);
}

// Round 2
// 934.080 us; speedup vs baseline: 4.1640x; 4.1640x over previous
//
#include <hip/hip_runtime.h>

#define HEADS 4

// ---------------- GEMM: C[M,Ncols] = A[M,K] @ B[K,Ncols] ----------------
__global__ __launch_bounds__(256)
void gemm_k(const float* __restrict__ A, const float* __restrict__ B,
            float* __restrict__ C, int M, int K, int Ncols) {
    constexpr int BM = 128, BN = 32, BK = 32;
    __shared__ float As[BK][BM];
    __shared__ float Bs[BK][BN];
    const int m0 = blockIdx.x * BM;
    const int n0 = blockIdx.y * BN;
    const int tid = threadIdx.x;
    const int ty = tid >> 3;
    const int tx = tid & 7;
    float acc[4][4] = {};
    for (int kt = 0; kt < K; kt += BK) {
        #pragma unroll
        for (int it = 0; it < 4; ++it) {
            int i = tid + 256 * it;
            int row = i >> 3;
            int kc = (i & 7) * 4;
            int grow = m0 + row;
            float4 v = make_float4(0.f, 0.f, 0.f, 0.f);
            if (grow < M)
                v = *(const float4*)&A[(size_t)grow * K + kt + kc];
            As[kc + 0][row] = v.x;
            As[kc + 1][row] = v.y;
            As[kc + 2][row] = v.z;
            As[kc + 3][row] = v.w;
        }
        {
            int kr = tid >> 3;
            int nc = (tid & 7) * 4;
            *(float4*)&Bs[kr][nc] =
                *(const float4*)&B[(size_t)(kt + kr) * Ncols + n0 + nc];
        }
        __syncthreads();
        #pragma unroll
        for (int k = 0; k < BK; ++k) {
            float4 av = *(const float4*)&As[k][ty * 4];
            float4 bv = *(const float4*)&Bs[k][tx * 4];
            float a[4] = {av.x, av.y, av.z, av.w};
            float b[4] = {bv.x, bv.y, bv.z, bv.w};
            #pragma unroll
            for (int i = 0; i < 4; ++i)
                #pragma unroll
                for (int j = 0; j < 4; ++j)
                    acc[i][j] += a[i] * b[j];
        }
        __syncthreads();
    }
    #pragma unroll
    for (int i = 0; i < 4; ++i) {
        int grow = m0 + ty * 4 + i;
        if (grow < M) {
            float4 v = make_float4(acc[i][0], acc[i][1], acc[i][2], acc[i][3]);
            *(float4*)&C[(size_t)grow * Ncols + n0 + tx * 4] = v;
        }
    }
}

// ---------------- per-node alpha + sigmoid ----------------
__global__ __launch_bounds__(256)
void alpha_k(const float* __restrict__ xh, const float* __restrict__ attq,
             float* __restrict__ sa, int n, int C, int HC) {
    const int t = blockIdx.x * blockDim.x + threadIdx.x;
    if (t >= n * HEADS) return;
    const int nd = t >> 2, h = t & 3;
    const float* xr = &xh[(size_t)nd * HC + h * C];
    const float* q = &attq[h * C];
    float s = 0.f;
    for (int c = 0; c < C; c += 4) {
        float4 a = *(const float4*)&xr[c];
        float4 b = *(const float4*)&q[c];
        s += a.x * b.x + a.y * b.y + a.z * b.z + a.w * b.w;
    }
    sa[t] = 1.0f / (1.0f + expf(-s));
}

// ---------------- CSR build (dst-sorted), once per launch ----------------
__global__ __launch_bounds__(256)
void hist_k(const int* __restrict__ dst, int* __restrict__ deg, int E) {
    int e = blockIdx.x * 256 + threadIdx.x;
    if (e < E) atomicAdd(&deg[dst[e]], 1);
}

__global__ __launch_bounds__(256)
void scan1_k(const int* __restrict__ deg, int* __restrict__ ro,
             int* __restrict__ bsum, int n) {
    __shared__ int s[256];
    int i = blockIdx.x * 256 + threadIdx.x;
    int v = (i < n) ? deg[i] : 0;
    s[threadIdx.x] = v;
    __syncthreads();
    for (int off = 1; off < 256; off <<= 1) {
        int t = (threadIdx.x >= off) ? s[threadIdx.x - off] : 0;
        __syncthreads();
        s[threadIdx.x] += t;
        __syncthreads();
    }
    if (i < n) ro[i] = s[threadIdx.x] - v;  // exclusive within block
    if (threadIdx.x == 255) bsum[blockIdx.x] = s[255];
}

__global__ __launch_bounds__(256)
void scan2_k(int* __restrict__ bsum, int nb) {
    __shared__ int s[256];
    int v = (threadIdx.x < nb) ? bsum[threadIdx.x] : 0;
    s[threadIdx.x] = v;
    __syncthreads();
    for (int off = 1; off < 256; off <<= 1) {
        int t = (threadIdx.x >= off) ? s[threadIdx.x - off] : 0;
        __syncthreads();
        s[threadIdx.x] += t;
        __syncthreads();
    }
    if (threadIdx.x < nb) bsum[threadIdx.x] = s[threadIdx.x] - v;  // exclusive
}

__global__ __launch_bounds__(256)
void scan3_k(int* __restrict__ ro, int* __restrict__ cur,
             const int* __restrict__ bsum, int n, int E) {
    int i = blockIdx.x * 256 + threadIdx.x;
    if (i < n) {
        int r = ro[i] + bsum[i >> 8];
        ro[i] = r;
        cur[i] = r;
    }
    if (i == 0) ro[n] = E;
}

__global__ __launch_bounds__(256)
void scatter_idx_k(const int* __restrict__ src, const int* __restrict__ dst,
                   int* __restrict__ cur, int* __restrict__ csr_src,
                   int* __restrict__ csr_dst, int E) {
    int e = blockIdx.x * 256 + threadIdx.x;
    if (e >= E) return;
    int d = dst[e];
    int pos = atomicAdd(&cur[d], 1);
    csr_src[pos] = src[e];
    csr_dst[pos] = d;
}

// ---------------- per-(CSR-slot,head) logits ----------------
template <int C>
__global__ __launch_bounds__(256)
void logit_csr_k(const int* __restrict__ csr_src, const int* __restrict__ csr_dst,
                 const float* __restrict__ xh, const float* __restrict__ sa,
                 const float* __restrict__ attv, float* __restrict__ exb, int E) {
    constexpr int HC = 4 * C;
    __shared__ float av[HC];
    for (int i = threadIdx.x; i < HC; i += 256) av[i] = attv[i];
    __syncthreads();
    const int t = blockIdx.x * 256 + threadIdx.x;
    if (t >= E * HEADS) return;
    const int j = t >> 2, h = t & 3;
    const int si = csr_src[j], di = csr_dst[j];
    const float wa = 1.0f - fabsf(sa[di * 4 + h] - sa[si * 4 + h]);
    const float* xs = &xh[(size_t)si * HC + h * C];
    const float* xd = &xh[(size_t)di * HC + h * C];
    float wb = 0.f;
    #pragma unroll
    for (int c = 0; c < C; c += 4) {
        float4 a = *(const float4*)&xs[c];
        float4 b = *(const float4*)&xd[c];
        float v0 = a.x + b.x; v0 = v0 > 0.f ? v0 : 0.01f * v0;
        float v1 = a.y + b.y; v1 = v1 > 0.f ? v1 : 0.01f * v1;
        float v2 = a.z + b.z; v2 = v2 > 0.f ? v2 : 0.01f * v2;
        float v3 = a.w + b.w; v3 = v3 > 0.f ? v3 : 0.01f * v3;
        wb += av[h * C + c] * v0 + av[h * C + c + 1] * v1 +
              av[h * C + c + 2] * v2 + av[h * C + c + 3] * v3;
    }
    exb[t] = wa * wb;
}

// ---------------- per-(node,head) softmax: wave-reduce max/sum ----------------
__global__ __launch_bounds__(256)
void softmax_seg_k(const int* __restrict__ ro, float* __restrict__ exb,
                   float* __restrict__ inv_s, int n) {
    const int w = blockIdx.x * 4 + (threadIdx.x >> 6);
    const int lane = threadIdx.x & 63;
    const int node = w >> 2, h = w & 3;
    if (node >= n) return;
    const int s0 = ro[node], s1 = ro[node + 1];
    float m = -3.4e38f;
    for (int j = s0 + lane; j < s1; j += 64) m = fmaxf(m, exb[j * 4 + h]);
    #pragma unroll
    for (int off = 32; off; off >>= 1) m = fmaxf(m, __shfl_xor(m, off, 64));
    float sum = 0.f;
    for (int j = s0 + lane; j < s1; j += 64) {
        float ex = expf(exb[j * 4 + h] - m);
        exb[j * 4 + h] = ex;
        sum += ex;
    }
    #pragma unroll
    for (int off = 32; off; off >>= 1) sum += __shfl_xor(sum, off, 64);
    if (lane == 0) inv_s[node * 4 + h] = 1.0f / (sum + 1e-16f);
}

// ---------------- per-node gather-aggregate + fused epilogue ----------------
// blockDim = 2*HC (two nodes per block). CONCAT: bias+ELU. else: head-mean+bias.
template <int C, bool CONCAT>
__global__ void aggregate_k(const int* __restrict__ ro, const int* __restrict__ csr_src,
                            const float* __restrict__ xh, const float* __restrict__ exb,
                            const float* __restrict__ inv_s, const float* __restrict__ bias,
                            float* __restrict__ outp, int n) {
    constexpr int HC = 4 * C;
    const int slot = threadIdx.x / HC;
    const int c = threadIdx.x % HC;
    const int h = c / C;
    const int node = blockIdx.x * 2 + slot;
    __shared__ float red[2][HC];

    float acc = 0.f;
    if (node < n) {
        const int s0 = ro[node], s1 = ro[node + 1];
        const float is = inv_s[node * 4 + h];
        for (int j = s0; j < s1; ++j) {
            const int si = csr_src[j];
            const float wgt = exb[j * 4 + h] * is;
            acc += wgt * xh[(size_t)si * HC + c];
        }
    }
    if (CONCAT) {
        if (node < n) {
            float v = acc + bias[c];
            outp[(size_t)node * HC + c] = v > 0.f ? v : expf(v) - 1.0f;
        }
    } else {
        red[slot][c] = acc;
        __syncthreads();
        if (node < n && c < C) {
            outp[(size_t)node * C + c] =
                0.25f * (red[slot][c] + red[slot][c + C] +
                         red[slot][c + 2 * C] + red[slot][c + 3 * C]) + bias[c];
        }
    }
}

extern "C" void kernel_launch(void* const* d_in, const int* in_sizes, int n_in,
                              void* d_out, int out_size, void* d_ws, size_t ws_size,
                              hipStream_t stream) {
    const float* x      = (const float*)d_in[0];
    const int*   src    = (const int*)d_in[1];
    const int*   dst    = (const int*)d_in[2];
    const float* lin1   = (const float*)d_in[3];
    const float* att_q1 = (const float*)d_in[4];
    const float* att_v1 = (const float*)d_in[5];
    const float* bias1  = (const float*)d_in[6];
    const float* lin2   = (const float*)d_in[7];
    const float* att_q2 = (const float*)d_in[8];
    const float* att_v2 = (const float*)d_in[9];
    const float* bias2  = (const float*)d_in[10];
    float* outp = (float*)d_out;

    const int n = in_sizes[0] / 256;
    const int E = in_sizes[1];
    const int nh = n * HEADS;
    const int NB = (n + 255) / 256;

    char* wsb = (char*)d_ws;
    size_t o = 0;
    float* xh     = (float*)(wsb + o); o += (size_t)n * 160 * 4;
    float* accb   = (float*)(wsb + o); o += (size_t)n * 160 * 4;
    float* sa     = (float*)(wsb + o); o += (size_t)nh * 4;
    float* inv_s  = (float*)(wsb + o); o += (size_t)nh * 4;
    float* exb    = (float*)(wsb + o); o += (size_t)E * HEADS * 4;
    int* csr_src  = (int*)(wsb + o); o += (size_t)E * 4;
    int* csr_dst  = (int*)(wsb + o); o += (size_t)E * 4;
    int* deg      = (int*)(wsb + o); o += (size_t)n * 4;
    int* ro       = (int*)(wsb + o); o += (size_t)(n + 1) * 4;
    int* cur      = (int*)(wsb + o); o += (size_t)n * 4;
    int* bsum     = (int*)(wsb + o); o += 256 * 4;

    dim3 blk(256);
    const int EG = (E + 255) / 256;

    // ---- CSR build (dst is layer-invariant: build once, use twice) ----
    hipMemsetAsync(deg, 0, (size_t)n * 4, stream);
    hist_k<<<EG, blk, 0, stream>>>(dst, deg, E);
    scan1_k<<<NB, blk, 0, stream>>>(deg, ro, bsum, n);
    scan2_k<<<1, blk, 0, stream>>>(bsum, NB);
    scan3_k<<<NB, blk, 0, stream>>>(ro, cur, bsum, n, E);
    scatter_idx_k<<<EG, blk, 0, stream>>>(src, dst, cur, csr_src, csr_dst, E);

    // ================= layer 1: C=32, HC=128, K=256 =================
    gemm_k<<<dim3((n + 127) / 128, 128 / 32), blk, 0, stream>>>(x, lin1, xh, n, 256, 128);
    alpha_k<<<(nh + 255) / 256, blk, 0, stream>>>(xh, att_q1, sa, n, 32, 128);
    logit_csr_k<32><<<(E * HEADS + 255) / 256, blk, 0, stream>>>(csr_src, csr_dst, xh, sa, att_v1, exb, E);
    softmax_seg_k<<<(nh + 3) / 4, blk, 0, stream>>>(ro, exb, inv_s, n);
    aggregate_k<32, true><<<(n + 1) / 2, dim3(256), 0, stream>>>(ro, csr_src, xh, exb, inv_s, bias1, accb, n);

    // ================= layer 2: C=40, HC=160, K=128 =================
    gemm_k<<<dim3((n + 127) / 128, 160 / 32), blk, 0, stream>>>(accb, lin2, xh, n, 128, 160);
    alpha_k<<<(nh + 255) / 256, blk, 0, stream>>>(xh, att_q2, sa, n, 40, 160);
    logit_csr_k<40><<<(E * HEADS + 255) / 256, blk, 0, stream>>>(csr_src, csr_dst, xh, sa, att_v2, exb, E);
    softmax_seg_k<<<(nh + 3) / 4, blk, 0, stream>>>(ro, exb, inv_s, n);
    aggregate_k<40, false><<<(n + 1) / 2, dim3(320), 0, stream>>>(ro, csr_src, xh, exb, inv_s, bias2, outp, n);
}

// Round 3
// 678.761 us; speedup vs baseline: 5.7302x; 1.3762x over previous
//
#include <hip/hip_runtime.h>

#define HEADS 4

// ---------------- GEMM: C[M,Ncols] = A[M,K] @ B[K,Ncols] ----------------
__global__ __launch_bounds__(256)
void gemm_k(const float* __restrict__ A, const float* __restrict__ B,
            float* __restrict__ C, int M, int K, int Ncols) {
    constexpr int BM = 128, BN = 32, BK = 32;
    __shared__ float As[BK][BM];
    __shared__ float Bs[BK][BN];
    const int m0 = blockIdx.x * BM;
    const int n0 = blockIdx.y * BN;
    const int tid = threadIdx.x;
    const int ty = tid >> 3;
    const int tx = tid & 7;
    float acc[4][4] = {};
    for (int kt = 0; kt < K; kt += BK) {
        #pragma unroll
        for (int it = 0; it < 4; ++it) {
            int i = tid + 256 * it;
            int row = i >> 3;
            int kc = (i & 7) * 4;
            int grow = m0 + row;
            float4 v = make_float4(0.f, 0.f, 0.f, 0.f);
            if (grow < M)
                v = *(const float4*)&A[(size_t)grow * K + kt + kc];
            As[kc + 0][row] = v.x;
            As[kc + 1][row] = v.y;
            As[kc + 2][row] = v.z;
            As[kc + 3][row] = v.w;
        }
        {
            int kr = tid >> 3;
            int nc = (tid & 7) * 4;
            *(float4*)&Bs[kr][nc] =
                *(const float4*)&B[(size_t)(kt + kr) * Ncols + n0 + nc];
        }
        __syncthreads();
        #pragma unroll
        for (int k = 0; k < BK; ++k) {
            float4 av = *(const float4*)&As[k][ty * 4];
            float4 bv = *(const float4*)&Bs[k][tx * 4];
            float a[4] = {av.x, av.y, av.z, av.w};
            float b[4] = {bv.x, bv.y, bv.z, bv.w};
            #pragma unroll
            for (int i = 0; i < 4; ++i)
                #pragma unroll
                for (int j = 0; j < 4; ++j)
                    acc[i][j] += a[i] * b[j];
        }
        __syncthreads();
    }
    #pragma unroll
    for (int i = 0; i < 4; ++i) {
        int grow = m0 + ty * 4 + i;
        if (grow < M) {
            float4 v = make_float4(acc[i][0], acc[i][1], acc[i][2], acc[i][3]);
            *(float4*)&C[(size_t)grow * Ncols + n0 + tx * 4] = v;
        }
    }
}

// ---------------- per-node alpha + sigmoid ----------------
__global__ __launch_bounds__(256)
void alpha_k(const float* __restrict__ xh, const float* __restrict__ attq,
             float* __restrict__ sa, int n, int C, int HC) {
    const int t = blockIdx.x * blockDim.x + threadIdx.x;
    if (t >= n * HEADS) return;
    const int nd = t >> 2, h = t & 3;
    const float* xr = &xh[(size_t)nd * HC + h * C];
    const float* q = &attq[h * C];
    float s = 0.f;
    for (int c = 0; c < C; c += 4) {
        float4 a = *(const float4*)&xr[c];
        float4 b = *(const float4*)&q[c];
        s += a.x * b.x + a.y * b.y + a.z * b.z + a.w * b.w;
    }
    sa[t] = 1.0f / (1.0f + expf(-s));
}

// ---------------- CSR build (dst-sorted), once per launch ----------------
__global__ __launch_bounds__(256)
void hist_k(const int* __restrict__ dst, int* __restrict__ deg, int E) {
    int e = blockIdx.x * 256 + threadIdx.x;
    if (e < E) atomicAdd(&deg[dst[e]], 1);
}

__global__ __launch_bounds__(256)
void scan1_k(const int* __restrict__ deg, int* __restrict__ ro,
             int* __restrict__ bsum, int n) {
    __shared__ int s[256];
    int i = blockIdx.x * 256 + threadIdx.x;
    int v = (i < n) ? deg[i] : 0;
    s[threadIdx.x] = v;
    __syncthreads();
    for (int off = 1; off < 256; off <<= 1) {
        int t = (threadIdx.x >= off) ? s[threadIdx.x - off] : 0;
        __syncthreads();
        s[threadIdx.x] += t;
        __syncthreads();
    }
    if (i < n) ro[i] = s[threadIdx.x] - v;
    if (threadIdx.x == 255) bsum[blockIdx.x] = s[255];
}

__global__ __launch_bounds__(256)
void scan2_k(int* __restrict__ bsum, int nb) {
    __shared__ int s[256];
    int v = (threadIdx.x < nb) ? bsum[threadIdx.x] : 0;
    s[threadIdx.x] = v;
    __syncthreads();
    for (int off = 1; off < 256; off <<= 1) {
        int t = (threadIdx.x >= off) ? s[threadIdx.x - off] : 0;
        __syncthreads();
        s[threadIdx.x] += t;
        __syncthreads();
    }
    if (threadIdx.x < nb) bsum[threadIdx.x] = s[threadIdx.x] - v;
}

__global__ __launch_bounds__(256)
void scan3_k(int* __restrict__ ro, int* __restrict__ cur,
             const int* __restrict__ bsum, int n, int E) {
    int i = blockIdx.x * 256 + threadIdx.x;
    if (i < n) {
        int r = ro[i] + bsum[i >> 8];
        ro[i] = r;
        cur[i] = r;
    }
    if (i == 0) ro[n] = E;
}

__global__ __launch_bounds__(256)
void scatter_idx_k(const int* __restrict__ src, const int* __restrict__ dst,
                   int* __restrict__ cur, int* __restrict__ csr_src,
                   int* __restrict__ csr_dst, int E) {
    int e = blockIdx.x * 256 + threadIdx.x;
    if (e >= E) return;
    int d = dst[e];
    int pos = atomicAdd(&cur[d], 1);
    csr_src[pos] = src[e];
    csr_dst[pos] = d;
}

// ---------------- per-(CSR-slot,head) logits ----------------
template <int C>
__global__ __launch_bounds__(256)
void logit_csr_k(const int* __restrict__ csr_src, const int* __restrict__ csr_dst,
                 const float* __restrict__ xh, const float* __restrict__ sa,
                 const float* __restrict__ attv, float* __restrict__ exb, int E) {
    constexpr int HC = 4 * C;
    __shared__ float av[HC];
    for (int i = threadIdx.x; i < HC; i += 256) av[i] = attv[i];
    __syncthreads();
    const int t = blockIdx.x * 256 + threadIdx.x;
    if (t >= E * HEADS) return;
    const int j = t >> 2, h = t & 3;
    const int si = csr_src[j], di = csr_dst[j];
    const float wa = 1.0f - fabsf(sa[di * 4 + h] - sa[si * 4 + h]);
    const float* xs = &xh[(size_t)si * HC + h * C];
    const float* xd = &xh[(size_t)di * HC + h * C];
    float wb = 0.f;
    #pragma unroll
    for (int c = 0; c < C; c += 4) {
        float4 a = *(const float4*)&xs[c];
        float4 b = *(const float4*)&xd[c];
        float v0 = a.x + b.x; v0 = v0 > 0.f ? v0 : 0.01f * v0;
        float v1 = a.y + b.y; v1 = v1 > 0.f ? v1 : 0.01f * v1;
        float v2 = a.z + b.z; v2 = v2 > 0.f ? v2 : 0.01f * v2;
        float v3 = a.w + b.w; v3 = v3 > 0.f ? v3 : 0.01f * v3;
        wb += av[h * C + c] * v0 + av[h * C + c + 1] * v1 +
              av[h * C + c + 2] * v2 + av[h * C + c + 3] * v3;
    }
    exb[t] = wa * wb;
}

// ---------------- per-(node,head) softmax: wave-reduce max/sum ----------------
__global__ __launch_bounds__(256)
void softmax_seg_k(const int* __restrict__ ro, float* __restrict__ exb,
                   float* __restrict__ inv_s, int n) {
    const int w = blockIdx.x * 4 + (threadIdx.x >> 6);
    const int lane = threadIdx.x & 63;
    const int node = w >> 2, h = w & 3;
    if (node >= n) return;
    const int s0 = ro[node], s1 = ro[node + 1];
    float m = -3.4e38f;
    for (int j = s0 + lane; j < s1; j += 64) m = fmaxf(m, exb[j * 4 + h]);
    #pragma unroll
    for (int off = 32; off; off >>= 1) m = fmaxf(m, __shfl_xor(m, off, 64));
    float sum = 0.f;
    for (int j = s0 + lane; j < s1; j += 64) {
        float ex = expf(exb[j * 4 + h] - m);
        exb[j * 4 + h] = ex;
        sum += ex;
    }
    #pragma unroll
    for (int off = 32; off; off >>= 1) sum += __shfl_xor(sum, off, 64);
    if (lane == 0) inv_s[node * 4 + h] = 1.0f / (sum + 1e-16f);
}

// ---------------- per-node gather-aggregate + fused epilogue ----------------
// Each node is served by C threads, each owning ONE float4 chunk of the
// HC-float row. 8 nodes per block. 4-edge unroll for memory-level parallelism.
template <int C, bool CONCAT>
__global__ void aggregate_k(const int* __restrict__ ro, const int* __restrict__ csr_src,
                            const float* __restrict__ xh, const float* __restrict__ exb,
                            const float* __restrict__ inv_s, const float* __restrict__ bias,
                            float* __restrict__ outp, int n) {
    constexpr int HC = 4 * C;
    constexpr int QH = C / 4;            // float4 chunks per head
    const int slot = threadIdx.x / C;    // 0..7
    const int q = threadIdx.x % C;       // float4 chunk 0..C-1
    const int h = q / QH;                // head
    const int node = blockIdx.x * 8 + slot;
    __shared__ float4 red[8][C];

    const float4* __restrict__ xh4 = (const float4*)xh;
    float4 acc = make_float4(0.f, 0.f, 0.f, 0.f);

    if (node < n) {
        const int s0 = ro[node], s1 = ro[node + 1];
        int j = s0;
        for (; j + 4 <= s1; j += 4) {
            const int i0 = csr_src[j], i1 = csr_src[j + 1];
            const int i2 = csr_src[j + 2], i3 = csr_src[j + 3];
            const float w0 = exb[(j + 0) * 4 + h];
            const float w1 = exb[(j + 1) * 4 + h];
            const float w2 = exb[(j + 2) * 4 + h];
            const float w3 = exb[(j + 3) * 4 + h];
            const float4 v0 = xh4[(size_t)i0 * C + q];
            const float4 v1 = xh4[(size_t)i1 * C + q];
            const float4 v2 = xh4[(size_t)i2 * C + q];
            const float4 v3 = xh4[(size_t)i3 * C + q];
            acc.x += w0 * v0.x + w1 * v1.x + w2 * v2.x + w3 * v3.x;
            acc.y += w0 * v0.y + w1 * v1.y + w2 * v2.y + w3 * v3.y;
            acc.z += w0 * v0.z + w1 * v1.z + w2 * v2.z + w3 * v3.z;
            acc.w += w0 * v0.w + w1 * v1.w + w2 * v2.w + w3 * v3.w;
        }
        for (; j < s1; ++j) {
            const int i0 = csr_src[j];
            const float w0 = exb[j * 4 + h];
            const float4 v0 = xh4[(size_t)i0 * C + q];
            acc.x += w0 * v0.x;
            acc.y += w0 * v0.y;
            acc.z += w0 * v0.z;
            acc.w += w0 * v0.w;
        }
        const float is = inv_s[node * 4 + h];
        acc.x *= is; acc.y *= is; acc.z *= is; acc.w *= is;
    }

    if (CONCAT) {
        if (node < n) {
            const float4 b = *(const float4*)&bias[q * 4];
            float4 v = make_float4(acc.x + b.x, acc.y + b.y, acc.z + b.z, acc.w + b.w);
            v.x = v.x > 0.f ? v.x : expf(v.x) - 1.0f;
            v.y = v.y > 0.f ? v.y : expf(v.y) - 1.0f;
            v.z = v.z > 0.f ? v.z : expf(v.z) - 1.0f;
            v.w = v.w > 0.f ? v.w : expf(v.w) - 1.0f;
            *(float4*)&outp[(size_t)node * HC + q * 4] = v;
        }
    } else {
        red[slot][q] = acc;
        __syncthreads();
        if (node < n && q < QH) {
            const float4 a0 = red[slot][q];
            const float4 a1 = red[slot][q + QH];
            const float4 a2 = red[slot][q + 2 * QH];
            const float4 a3 = red[slot][q + 3 * QH];
            const float4 b = *(const float4*)&bias[q * 4];
            float4 v;
            v.x = 0.25f * (a0.x + a1.x + a2.x + a3.x) + b.x;
            v.y = 0.25f * (a0.y + a1.y + a2.y + a3.y) + b.y;
            v.z = 0.25f * (a0.z + a1.z + a2.z + a3.z) + b.z;
            v.w = 0.25f * (a0.w + a1.w + a2.w + a3.w) + b.w;
            *(float4*)&outp[(size_t)node * C + q * 4] = v;
        }
    }
}

extern "C" void kernel_launch(void* const* d_in, const int* in_sizes, int n_in,
                              void* d_out, int out_size, void* d_ws, size_t ws_size,
                              hipStream_t stream) {
    const float* x      = (const float*)d_in[0];
    const int*   src    = (const int*)d_in[1];
    const int*   dst    = (const int*)d_in[2];
    const float* lin1   = (const float*)d_in[3];
    const float* att_q1 = (const float*)d_in[4];
    const float* att_v1 = (const float*)d_in[5];
    const float* bias1  = (const float*)d_in[6];
    const float* lin2   = (const float*)d_in[7];
    const float* att_q2 = (const float*)d_in[8];
    const float* att_v2 = (const float*)d_in[9];
    const float* bias2  = (const float*)d_in[10];
    float* outp = (float*)d_out;

    const int n = in_sizes[0] / 256;
    const int E = in_sizes[1];
    const int nh = n * HEADS;
    const int NB = (n + 255) / 256;

    char* wsb = (char*)d_ws;
    size_t o = 0;
    float* xh     = (float*)(wsb + o); o += (size_t)n * 160 * 4;
    float* accb   = (float*)(wsb + o); o += (size_t)n * 160 * 4;
    float* sa     = (float*)(wsb + o); o += (size_t)nh * 4;
    float* inv_s  = (float*)(wsb + o); o += (size_t)nh * 4;
    float* exb    = (float*)(wsb + o); o += (size_t)E * HEADS * 4;
    int* csr_src  = (int*)(wsb + o); o += (size_t)E * 4;
    int* csr_dst  = (int*)(wsb + o); o += (size_t)E * 4;
    int* deg      = (int*)(wsb + o); o += (size_t)n * 4;
    int* ro       = (int*)(wsb + o); o += (size_t)(n + 1) * 4;
    int* cur      = (int*)(wsb + o); o += (size_t)n * 4;
    int* bsum     = (int*)(wsb + o); o += 256 * 4;

    dim3 blk(256);
    const int EG = (E + 255) / 256;

    // ---- CSR build (dst is layer-invariant: build once, use twice) ----
    hipMemsetAsync(deg, 0, (size_t)n * 4, stream);
    hist_k<<<EG, blk, 0, stream>>>(dst, deg, E);
    scan1_k<<<NB, blk, 0, stream>>>(deg, ro, bsum, n);
    scan2_k<<<1, blk, 0, stream>>>(bsum, NB);
    scan3_k<<<NB, blk, 0, stream>>>(ro, cur, bsum, n, E);
    scatter_idx_k<<<EG, blk, 0, stream>>>(src, dst, cur, csr_src, csr_dst, E);

    // ================= layer 1: C=32, HC=128, K=256 =================
    gemm_k<<<dim3((n + 127) / 128, 128 / 32), blk, 0, stream>>>(x, lin1, xh, n, 256, 128);
    alpha_k<<<(nh + 255) / 256, blk, 0, stream>>>(xh, att_q1, sa, n, 32, 128);
    logit_csr_k<32><<<(E * HEADS + 255) / 256, blk, 0, stream>>>(csr_src, csr_dst, xh, sa, att_v1, exb, E);
    softmax_seg_k<<<(nh + 3) / 4, blk, 0, stream>>>(ro, exb, inv_s, n);
    aggregate_k<32, true><<<(n + 7) / 8, dim3(256), 0, stream>>>(ro, csr_src, xh, exb, inv_s, bias1, accb, n);

    // ================= layer 2: C=40, HC=160, K=128 =================
    gemm_k<<<dim3((n + 127) / 128, 160 / 32), blk, 0, stream>>>(accb, lin2, xh, n, 128, 160);
    alpha_k<<<(nh + 255) / 256, blk, 0, stream>>>(xh, att_q2, sa, n, 40, 160);
    logit_csr_k<40><<<(E * HEADS + 255) / 256, blk, 0, stream>>>(csr_src, csr_dst, xh, sa, att_v2, exb, E);
    softmax_seg_k<<<(nh + 3) / 4, blk, 0, stream>>>(ro, exb, inv_s, n);
    aggregate_k<40, false><<<(n + 7) / 8, dim3(320), 0, stream>>>(ro, csr_src, xh, exb, inv_s, bias2, outp, n);
}

// Round 4
// 653.698 us; speedup vs baseline: 5.9499x; 1.0383x over previous
//
#include <hip/hip_runtime.h>

#define HEADS 4

// ---------------- GEMM: C[M,Ncols] = A[M,K] @ B[K,Ncols] ----------------
__global__ __launch_bounds__(256)
void gemm_k(const float* __restrict__ A, const float* __restrict__ B,
            float* __restrict__ C, int M, int K, int Ncols) {
    constexpr int BM = 128, BN = 32, BK = 32;
    __shared__ float As[BK][BM];
    __shared__ float Bs[BK][BN];
    const int m0 = blockIdx.x * BM;
    const int n0 = blockIdx.y * BN;
    const int tid = threadIdx.x;
    const int ty = tid >> 3;
    const int tx = tid & 7;
    float acc[4][4] = {};
    for (int kt = 0; kt < K; kt += BK) {
        #pragma unroll
        for (int it = 0; it < 4; ++it) {
            int i = tid + 256 * it;
            int row = i >> 3;
            int kc = (i & 7) * 4;
            int grow = m0 + row;
            float4 v = make_float4(0.f, 0.f, 0.f, 0.f);
            if (grow < M)
                v = *(const float4*)&A[(size_t)grow * K + kt + kc];
            As[kc + 0][row] = v.x;
            As[kc + 1][row] = v.y;
            As[kc + 2][row] = v.z;
            As[kc + 3][row] = v.w;
        }
        {
            int kr = tid >> 3;
            int nc = (tid & 7) * 4;
            *(float4*)&Bs[kr][nc] =
                *(const float4*)&B[(size_t)(kt + kr) * Ncols + n0 + nc];
        }
        __syncthreads();
        #pragma unroll
        for (int k = 0; k < BK; ++k) {
            float4 av = *(const float4*)&As[k][ty * 4];
            float4 bv = *(const float4*)&Bs[k][tx * 4];
            float a[4] = {av.x, av.y, av.z, av.w};
            float b[4] = {bv.x, bv.y, bv.z, bv.w};
            #pragma unroll
            for (int i = 0; i < 4; ++i)
                #pragma unroll
                for (int j = 0; j < 4; ++j)
                    acc[i][j] += a[i] * b[j];
        }
        __syncthreads();
    }
    #pragma unroll
    for (int i = 0; i < 4; ++i) {
        int grow = m0 + ty * 4 + i;
        if (grow < M) {
            float4 v = make_float4(acc[i][0], acc[i][1], acc[i][2], acc[i][3]);
            *(float4*)&C[(size_t)grow * Ncols + n0 + tx * 4] = v;
        }
    }
}

// ---------------- per-node alpha + sigmoid ----------------
__global__ __launch_bounds__(256)
void alpha_k(const float* __restrict__ xh, const float* __restrict__ attq,
             float* __restrict__ sa, int n, int C, int HC) {
    const int t = blockIdx.x * blockDim.x + threadIdx.x;
    if (t >= n * HEADS) return;
    const int nd = t >> 2, h = t & 3;
    const float* xr = &xh[(size_t)nd * HC + h * C];
    const float* q = &attq[h * C];
    float s = 0.f;
    for (int c = 0; c < C; c += 4) {
        float4 a = *(const float4*)&xr[c];
        float4 b = *(const float4*)&q[c];
        s += a.x * b.x + a.y * b.y + a.z * b.z + a.w * b.w;
    }
    sa[t] = 1.0f / (1.0f + __expf(-s));
}

// ---------------- CSR build (dst-sorted), once per launch ----------------
__global__ __launch_bounds__(256)
void hist_k(const int* __restrict__ dst, int* __restrict__ deg, int E) {
    int e = blockIdx.x * 256 + threadIdx.x;
    if (e < E) atomicAdd(&deg[dst[e]], 1);
}

__global__ __launch_bounds__(256)
void scan1_k(const int* __restrict__ deg, int* __restrict__ ro,
             int* __restrict__ bsum, int n) {
    __shared__ int s[256];
    int i = blockIdx.x * 256 + threadIdx.x;
    int v = (i < n) ? deg[i] : 0;
    s[threadIdx.x] = v;
    __syncthreads();
    for (int off = 1; off < 256; off <<= 1) {
        int t = (threadIdx.x >= off) ? s[threadIdx.x - off] : 0;
        __syncthreads();
        s[threadIdx.x] += t;
        __syncthreads();
    }
    if (i < n) ro[i] = s[threadIdx.x] - v;
    if (threadIdx.x == 255) bsum[blockIdx.x] = s[255];
}

__global__ __launch_bounds__(256)
void scan2_k(int* __restrict__ bsum, int nb) {
    __shared__ int s[256];
    int v = (threadIdx.x < nb) ? bsum[threadIdx.x] : 0;
    s[threadIdx.x] = v;
    __syncthreads();
    for (int off = 1; off < 256; off <<= 1) {
        int t = (threadIdx.x >= off) ? s[threadIdx.x - off] : 0;
        __syncthreads();
        s[threadIdx.x] += t;
        __syncthreads();
    }
    if (threadIdx.x < nb) bsum[threadIdx.x] = s[threadIdx.x] - v;
}

__global__ __launch_bounds__(256)
void scan3_k(int* __restrict__ ro, int* __restrict__ cur,
             const int* __restrict__ bsum, int n, int E) {
    int i = blockIdx.x * 256 + threadIdx.x;
    if (i < n) {
        int r = ro[i] + bsum[i >> 8];
        ro[i] = r;
        cur[i] = r;
    }
    if (i == 0) ro[n] = E;
}

__global__ __launch_bounds__(256)
void scatter_idx_k(const int* __restrict__ src, const int* __restrict__ dst,
                   int* __restrict__ cur, int* __restrict__ csr_src, int E) {
    int e = blockIdx.x * 256 + threadIdx.x;
    if (e >= E) return;
    int d = dst[e];
    int pos = atomicAdd(&cur[d], 1);
    csr_src[pos] = src[e];
}

// ---------------- fused logit+softmax+aggregate+epilogue ----------------
// One wave per node. 16-edge chunks.
//   Logit mapping: lane = 4*e_loc + h  (16 edges x 4 heads)
//   Agg   mapping: lane = q (float4 chunk of HC row), head h_a = q/QH
// No LDS, no barriers: w/src handed across lanes via shuffles.
template <int C, bool CONCAT>
__global__ __launch_bounds__(256)
void fused_edge_k(const int* __restrict__ ro, const int* __restrict__ csr_src,
                  const float* __restrict__ xh, const float* __restrict__ sa,
                  const float* __restrict__ attv, const float* __restrict__ bias,
                  float* __restrict__ outp, int n) {
    constexpr int HC = 4 * C;
    constexpr int QH = C / 4;  // float4 chunks per head
    const int wid = threadIdx.x >> 6;
    const int lane = threadIdx.x & 63;
    const int node = blockIdx.x * 4 + wid;
    if (node >= n) return;

    const float4* __restrict__ xh4 = (const float4*)xh;
    const float4* __restrict__ av4 = (const float4*)attv;
    const int s0 = ro[node], s1 = ro[node + 1];

    // logit mapping
    const int e_loc = lane >> 2;
    const int h_l = lane & 3;
    const float sad = sa[node * 4 + h_l];

    // aggregation mapping
    const int q = lane;
    const int h_a = (q < C) ? (q / QH) : 0;

    float4 acc = make_float4(0.f, 0.f, 0.f, 0.f);
    float ssum = 0.f;

    for (int base = s0; base < s1; base += 16) {
        const int j = base + e_loc;
        const bool valid = (j < s1);
        float w = 0.f;
        int si = 0;
        if (valid) {
            si = csr_src[j];
            const float sas = sa[si * 4 + h_l];
            const float wa = 1.0f - fabsf(sad - sas);
            const float4* xs = &xh4[(size_t)si * C + h_l * QH];
            const float4* xd = &xh4[(size_t)node * C + h_l * QH];
            const float4* av = &av4[h_l * QH];
            float wb = 0.f;
            #pragma unroll
            for (int i = 0; i < QH; ++i) {
                const float4 a = xs[i];
                const float4 b = xd[i];
                const float4 v = av[i];
                float t0 = a.x + b.x; t0 = t0 > 0.f ? t0 : 0.01f * t0;
                float t1 = a.y + b.y; t1 = t1 > 0.f ? t1 : 0.01f * t1;
                float t2 = a.z + b.z; t2 = t2 > 0.f ? t2 : 0.01f * t2;
                float t3 = a.w + b.w; t3 = t3 > 0.f ? t3 : 0.01f * t3;
                wb += v.x * t0 + v.y * t1 + v.z * t2 + v.w * t3;
            }
            const float l = fminf(wa * wb, 60.f);  // inf-guard only
            w = __expf(l);
            ssum += w;
        }
        // hand over to aggregation mapping
        const int rem = s1 - base;
        const int cnt = rem < 16 ? rem : 16;
        #pragma unroll 4
        for (int e = 0; e < cnt; ++e) {
            const float we = __shfl(w, e * 4 + h_a, 64);
            const int sie = __shfl(si, e * 4, 64);
            if (q < C) {
                const float4 v = xh4[(size_t)sie * C + q];
                acc.x += we * v.x;
                acc.y += we * v.y;
                acc.z += we * v.z;
                acc.w += we * v.w;
            }
        }
    }

    // per-head sum of weights: reduce across lanes sharing (lane & 3)
    #pragma unroll
    for (int off = 4; off < 64; off <<= 1) ssum += __shfl_xor(ssum, off, 64);
    const float stot = __shfl(ssum, h_a, 64);
    const float inv = 1.0f / (stot + 1e-20f);
    acc.x *= inv; acc.y *= inv; acc.z *= inv; acc.w *= inv;

    if (CONCAT) {
        if (q < C) {
            const float4 b = ((const float4*)bias)[q];
            float4 v = make_float4(acc.x + b.x, acc.y + b.y, acc.z + b.z, acc.w + b.w);
            v.x = v.x > 0.f ? v.x : __expf(v.x) - 1.0f;
            v.y = v.y > 0.f ? v.y : __expf(v.y) - 1.0f;
            v.z = v.z > 0.f ? v.z : __expf(v.z) - 1.0f;
            v.w = v.w > 0.f ? v.w : __expf(v.w) - 1.0f;
            *(float4*)&outp[(size_t)node * HC + q * 4] = v;
        }
    } else {
        // head-mean via shuffles: lanes q<QH gather the other 3 heads' chunks
        const int qq = (q < QH) ? q : 0;
        const float x1 = __shfl(acc.x, qq + QH, 64);
        const float y1 = __shfl(acc.y, qq + QH, 64);
        const float z1 = __shfl(acc.z, qq + QH, 64);
        const float w1 = __shfl(acc.w, qq + QH, 64);
        const float x2 = __shfl(acc.x, qq + 2 * QH, 64);
        const float y2 = __shfl(acc.y, qq + 2 * QH, 64);
        const float z2 = __shfl(acc.z, qq + 2 * QH, 64);
        const float w2 = __shfl(acc.w, qq + 2 * QH, 64);
        const float x3 = __shfl(acc.x, qq + 3 * QH, 64);
        const float y3 = __shfl(acc.y, qq + 3 * QH, 64);
        const float z3 = __shfl(acc.z, qq + 3 * QH, 64);
        const float w3 = __shfl(acc.w, qq + 3 * QH, 64);
        if (q < QH) {
            const float4 b = ((const float4*)bias)[q];
            float4 v;
            v.x = 0.25f * (acc.x + x1 + x2 + x3) + b.x;
            v.y = 0.25f * (acc.y + y1 + y2 + y3) + b.y;
            v.z = 0.25f * (acc.z + z1 + z2 + z3) + b.z;
            v.w = 0.25f * (acc.w + w1 + w2 + w3) + b.w;
            *(float4*)&outp[(size_t)node * C + q * 4] = v;
        }
    }
}

extern "C" void kernel_launch(void* const* d_in, const int* in_sizes, int n_in,
                              void* d_out, int out_size, void* d_ws, size_t ws_size,
                              hipStream_t stream) {
    const float* x      = (const float*)d_in[0];
    const int*   src    = (const int*)d_in[1];
    const int*   dst    = (const int*)d_in[2];
    const float* lin1   = (const float*)d_in[3];
    const float* att_q1 = (const float*)d_in[4];
    const float* att_v1 = (const float*)d_in[5];
    const float* bias1  = (const float*)d_in[6];
    const float* lin2   = (const float*)d_in[7];
    const float* att_q2 = (const float*)d_in[8];
    const float* att_v2 = (const float*)d_in[9];
    const float* bias2  = (const float*)d_in[10];
    float* outp = (float*)d_out;

    const int n = in_sizes[0] / 256;
    const int E = in_sizes[1];
    const int nh = n * HEADS;
    const int NB = (n + 255) / 256;

    char* wsb = (char*)d_ws;
    size_t o = 0;
    float* xh     = (float*)(wsb + o); o += (size_t)n * 160 * 4;
    float* accb   = (float*)(wsb + o); o += (size_t)n * 160 * 4;
    float* sa     = (float*)(wsb + o); o += (size_t)nh * 4;
    int* csr_src  = (int*)(wsb + o); o += (size_t)E * 4;
    int* deg      = (int*)(wsb + o); o += (size_t)n * 4;
    int* ro       = (int*)(wsb + o); o += (size_t)(n + 1) * 4;
    int* cur      = (int*)(wsb + o); o += (size_t)n * 4;
    int* bsum     = (int*)(wsb + o); o += 256 * 4;

    dim3 blk(256);
    const int EG = (E + 255) / 256;

    // ---- CSR build (dst is layer-invariant: build once, use twice) ----
    hipMemsetAsync(deg, 0, (size_t)n * 4, stream);
    hist_k<<<EG, blk, 0, stream>>>(dst, deg, E);
    scan1_k<<<NB, blk, 0, stream>>>(deg, ro, bsum, n);
    scan2_k<<<1, blk, 0, stream>>>(bsum, NB);
    scan3_k<<<NB, blk, 0, stream>>>(ro, cur, bsum, n, E);
    scatter_idx_k<<<EG, blk, 0, stream>>>(src, dst, cur, csr_src, E);

    // ================= layer 1: C=32, HC=128, K=256 =================
    gemm_k<<<dim3((n + 127) / 128, 128 / 32), blk, 0, stream>>>(x, lin1, xh, n, 256, 128);
    alpha_k<<<(nh + 255) / 256, blk, 0, stream>>>(xh, att_q1, sa, n, 32, 128);
    fused_edge_k<32, true><<<(n + 3) / 4, blk, 0, stream>>>(ro, csr_src, xh, sa, att_v1, bias1, accb, n);

    // ================= layer 2: C=40, HC=160, K=128 =================
    gemm_k<<<dim3((n + 127) / 128, 160 / 32), blk, 0, stream>>>(accb, lin2, xh, n, 128, 160);
    alpha_k<<<(nh + 255) / 256, blk, 0, stream>>>(xh, att_q2, sa, n, 40, 160);
    fused_edge_k<40, false><<<(n + 3) / 4, blk, 0, stream>>>(ro, csr_src, xh, sa, att_v2, bias2, outp, n);
}

// Round 5
// 530.195 us; speedup vs baseline: 7.3359x; 1.2329x over previous
//
#include <hip/hip_runtime.h>

#define HEADS 4

// ---------------- GEMM: C[M,Ncols] = A[M,K] @ B[K,Ncols] ----------------
__global__ __launch_bounds__(256)
void gemm_k(const float* __restrict__ A, const float* __restrict__ B,
            float* __restrict__ C, int M, int K, int Ncols) {
    constexpr int BM = 128, BN = 32, BK = 32;
    __shared__ float As[BK][BM];
    __shared__ float Bs[BK][BN];
    const int m0 = blockIdx.x * BM;
    const int n0 = blockIdx.y * BN;
    const int tid = threadIdx.x;
    const int ty = tid >> 3;
    const int tx = tid & 7;
    float acc[4][4] = {};
    for (int kt = 0; kt < K; kt += BK) {
        #pragma unroll
        for (int it = 0; it < 4; ++it) {
            int i = tid + 256 * it;
            int row = i >> 3;
            int kc = (i & 7) * 4;
            int grow = m0 + row;
            float4 v = make_float4(0.f, 0.f, 0.f, 0.f);
            if (grow < M)
                v = *(const float4*)&A[(size_t)grow * K + kt + kc];
            As[kc + 0][row] = v.x;
            As[kc + 1][row] = v.y;
            As[kc + 2][row] = v.z;
            As[kc + 3][row] = v.w;
        }
        {
            int kr = tid >> 3;
            int nc = (tid & 7) * 4;
            *(float4*)&Bs[kr][nc] =
                *(const float4*)&B[(size_t)(kt + kr) * Ncols + n0 + nc];
        }
        __syncthreads();
        #pragma unroll
        for (int k = 0; k < BK; ++k) {
            float4 av = *(const float4*)&As[k][ty * 4];
            float4 bv = *(const float4*)&Bs[k][tx * 4];
            float a[4] = {av.x, av.y, av.z, av.w};
            float b[4] = {bv.x, bv.y, bv.z, bv.w};
            #pragma unroll
            for (int i = 0; i < 4; ++i)
                #pragma unroll
                for (int j = 0; j < 4; ++j)
                    acc[i][j] += a[i] * b[j];
        }
        __syncthreads();
    }
    #pragma unroll
    for (int i = 0; i < 4; ++i) {
        int grow = m0 + ty * 4 + i;
        if (grow < M) {
            float4 v = make_float4(acc[i][0], acc[i][1], acc[i][2], acc[i][3]);
            *(float4*)&C[(size_t)grow * Ncols + n0 + tx * 4] = v;
        }
    }
}

// ---------------- per-node alpha + sigmoid ----------------
__global__ __launch_bounds__(256)
void alpha_k(const float* __restrict__ xh, const float* __restrict__ attq,
             float* __restrict__ sa, int n, int C, int HC) {
    const int t = blockIdx.x * blockDim.x + threadIdx.x;
    if (t >= n * HEADS) return;
    const int nd = t >> 2, h = t & 3;
    const float* xr = &xh[(size_t)nd * HC + h * C];
    const float* q = &attq[h * C];
    float s = 0.f;
    for (int c = 0; c < C; c += 4) {
        float4 a = *(const float4*)&xr[c];
        float4 b = *(const float4*)&q[c];
        s += a.x * b.x + a.y * b.y + a.z * b.z + a.w * b.w;
    }
    sa[t] = 1.0f / (1.0f + __expf(-s));
}

// ---------------- CSR build (dst-sorted), once per launch ----------------
__global__ __launch_bounds__(256)
void hist_k(const int* __restrict__ dst, int* __restrict__ deg, int E) {
    int e = blockIdx.x * 256 + threadIdx.x;
    if (e < E) atomicAdd(&deg[dst[e]], 1);
}

__global__ __launch_bounds__(256)
void scan1_k(const int* __restrict__ deg, int* __restrict__ ro,
             int* __restrict__ bsum, int n) {
    __shared__ int s[256];
    int i = blockIdx.x * 256 + threadIdx.x;
    int v = (i < n) ? deg[i] : 0;
    s[threadIdx.x] = v;
    __syncthreads();
    for (int off = 1; off < 256; off <<= 1) {
        int t = (threadIdx.x >= off) ? s[threadIdx.x - off] : 0;
        __syncthreads();
        s[threadIdx.x] += t;
        __syncthreads();
    }
    if (i < n) ro[i] = s[threadIdx.x] - v;
    if (threadIdx.x == 255) bsum[blockIdx.x] = s[255];
}

__global__ __launch_bounds__(256)
void scan2_k(int* __restrict__ bsum, int nb) {
    __shared__ int s[256];
    int v = (threadIdx.x < nb) ? bsum[threadIdx.x] : 0;
    s[threadIdx.x] = v;
    __syncthreads();
    for (int off = 1; off < 256; off <<= 1) {
        int t = (threadIdx.x >= off) ? s[threadIdx.x - off] : 0;
        __syncthreads();
        s[threadIdx.x] += t;
        __syncthreads();
    }
    if (threadIdx.x < nb) bsum[threadIdx.x] = s[threadIdx.x] - v;
}

__global__ __launch_bounds__(256)
void scan3_k(int* __restrict__ ro, int* __restrict__ cur,
             const int* __restrict__ bsum, int n, int E) {
    int i = blockIdx.x * 256 + threadIdx.x;
    if (i < n) {
        int r = ro[i] + bsum[i >> 8];
        ro[i] = r;
        cur[i] = r;
    }
    if (i == 0) ro[n] = E;
}

__global__ __launch_bounds__(256)
void scatter_idx_k(const int* __restrict__ src, const int* __restrict__ dst,
                   int* __restrict__ cur, int* __restrict__ csr_src, int E) {
    int e = blockIdx.x * 256 + threadIdx.x;
    if (e >= E) return;
    int d = dst[e];
    int pos = atomicAdd(&cur[d], 1);
    csr_src[pos] = src[e];
}

// ---------------- fused logit+softmax+aggregate+epilogue ----------------
// One wave per node. 64-edge super-chunks staged through LDS:
//   logit passes (lane = 4*e+h, 16 edges/pass) write w -> wbuf, si -> sibuf
//   agg loop (lane = float4 chunk) reads w/si from LDS (broadcast) and does
//   4 independent row-gathers per iteration. Zero shuffles in hot loop.
// DUAL (64/C>=2, i.e. C=32): lanes split even/odd edges, shfl_xor(32) combine.
template <int C, bool CONCAT>
__global__ __launch_bounds__(256)
void fused_edge_k(const int* __restrict__ ro, const int* __restrict__ csr_src,
                  const float* __restrict__ xh, const float* __restrict__ sa,
                  const float* __restrict__ attv, const float* __restrict__ bias,
                  float* __restrict__ outp, int n) {
    constexpr int HC = 4 * C;
    constexpr int QH = C / 4;        // float4 chunks per head
    constexpr int CHUNK = 64;        // edges per super-chunk
    constexpr bool DUAL = (C <= 32);
    const int wid = threadIdx.x >> 6;
    const int lane = threadIdx.x & 63;
    const int node = blockIdx.x * 4 + wid;

    __shared__ float wbuf[4][CHUNK * 4];
    __shared__ int sibuf[4][CHUNK];
    __shared__ float avs[HC];
    for (int i = threadIdx.x; i < HC; i += 256) avs[i] = attv[i];
    __syncthreads();
    if (node >= n) return;

    const float4* __restrict__ xh4 = (const float4*)xh;
    const float4* __restrict__ avs4 = (const float4*)avs;
    const int s0 = ro[node], s1 = ro[node + 1];

    // logit mapping
    const int e_loc = lane >> 2;
    const int h_l = lane & 3;
    const float sad = sa[node * 4 + h_l];

    // aggregation mapping
    const int half = DUAL ? (lane >> 5) : 0;
    const int q = DUAL ? (lane & 31) : lane;
    const int h_a = (q < C) ? (q / QH) : 0;

    float4 acc = make_float4(0.f, 0.f, 0.f, 0.f);
    float ssum = 0.f;

    for (int base = s0; base < s1; base += CHUNK) {
        const int cnt = min(CHUNK, s1 - base);
        const int npass = (cnt + 15) >> 4;
        // ---- logit passes: 16 edges x 4 heads per pass ----
        for (int p = 0; p < npass; ++p) {
            const int eidx = p * 16 + e_loc;
            const int j = base + eidx;
            float w = 0.f;
            int si = 0;
            if (j < s1) {
                si = csr_src[j];
                const float sas = sa[si * 4 + h_l];
                const float wa = 1.0f - fabsf(sad - sas);
                const float4* xs = &xh4[(size_t)si * C + h_l * QH];
                const float4* xd = &xh4[(size_t)node * C + h_l * QH];
                const float4* av = &avs4[h_l * QH];
                float wb = 0.f;
                #pragma unroll
                for (int i = 0; i < QH; ++i) {
                    const float4 a = xs[i];
                    const float4 b = xd[i];
                    const float4 v = av[i];
                    float t0 = a.x + b.x; t0 = t0 > 0.f ? t0 : 0.01f * t0;
                    float t1 = a.y + b.y; t1 = t1 > 0.f ? t1 : 0.01f * t1;
                    float t2 = a.z + b.z; t2 = t2 > 0.f ? t2 : 0.01f * t2;
                    float t3 = a.w + b.w; t3 = t3 > 0.f ? t3 : 0.01f * t3;
                    wb += v.x * t0 + v.y * t1 + v.z * t2 + v.w * t3;
                }
                w = __expf(fminf(wa * wb, 60.f));  // inf-guard only
                ssum += w;
            }
            wbuf[wid][eidx * 4 + h_l] = w;
            if (h_l == 0) sibuf[wid][eidx] = si;
        }
        // ---- aggregation: padded slots carry w=0/si=0, no guards ----
        const int padded = npass << 4;
        if (q < C) {
            if (DUAL) {
                for (int i = 0; i < padded; i += 8) {
                    const int e0 = i + half, e1 = i + half + 2;
                    const int e2 = i + half + 4, e3 = i + half + 6;
                    const int i0 = sibuf[wid][e0], i1 = sibuf[wid][e1];
                    const int i2 = sibuf[wid][e2], i3 = sibuf[wid][e3];
                    const float w0 = wbuf[wid][e0 * 4 + h_a];
                    const float w1 = wbuf[wid][e1 * 4 + h_a];
                    const float w2 = wbuf[wid][e2 * 4 + h_a];
                    const float w3 = wbuf[wid][e3 * 4 + h_a];
                    const float4 v0 = xh4[(size_t)i0 * C + q];
                    const float4 v1 = xh4[(size_t)i1 * C + q];
                    const float4 v2 = xh4[(size_t)i2 * C + q];
                    const float4 v3 = xh4[(size_t)i3 * C + q];
                    acc.x += w0 * v0.x + w1 * v1.x + w2 * v2.x + w3 * v3.x;
                    acc.y += w0 * v0.y + w1 * v1.y + w2 * v2.y + w3 * v3.y;
                    acc.z += w0 * v0.z + w1 * v1.z + w2 * v2.z + w3 * v3.z;
                    acc.w += w0 * v0.w + w1 * v1.w + w2 * v2.w + w3 * v3.w;
                }
            } else {
                for (int i = 0; i < padded; i += 4) {
                    const int i0 = sibuf[wid][i],     i1 = sibuf[wid][i + 1];
                    const int i2 = sibuf[wid][i + 2], i3 = sibuf[wid][i + 3];
                    const float w0 = wbuf[wid][(i + 0) * 4 + h_a];
                    const float w1 = wbuf[wid][(i + 1) * 4 + h_a];
                    const float w2 = wbuf[wid][(i + 2) * 4 + h_a];
                    const float w3 = wbuf[wid][(i + 3) * 4 + h_a];
                    const float4 v0 = xh4[(size_t)i0 * C + q];
                    const float4 v1 = xh4[(size_t)i1 * C + q];
                    const float4 v2 = xh4[(size_t)i2 * C + q];
                    const float4 v3 = xh4[(size_t)i3 * C + q];
                    acc.x += w0 * v0.x + w1 * v1.x + w2 * v2.x + w3 * v3.x;
                    acc.y += w0 * v0.y + w1 * v1.y + w2 * v2.y + w3 * v3.y;
                    acc.z += w0 * v0.z + w1 * v1.z + w2 * v2.z + w3 * v3.z;
                    acc.w += w0 * v0.w + w1 * v1.w + w2 * v2.w + w3 * v3.w;
                }
            }
        }
    }

    // combine dual halves
    if (DUAL) {
        acc.x += __shfl_xor(acc.x, 32, 64);
        acc.y += __shfl_xor(acc.y, 32, 64);
        acc.z += __shfl_xor(acc.z, 32, 64);
        acc.w += __shfl_xor(acc.w, 32, 64);
    }

    // per-head sum of weights: reduce across lanes sharing (lane & 3)
    #pragma unroll
    for (int off = 4; off < 64; off <<= 1) ssum += __shfl_xor(ssum, off, 64);
    const float stot = __shfl(ssum, h_a, 64);
    const float inv = 1.0f / (stot + 1e-20f);
    acc.x *= inv; acc.y *= inv; acc.z *= inv; acc.w *= inv;

    if (CONCAT) {
        if (q < C && half == 0) {
            const float4 b = ((const float4*)bias)[q];
            float4 v = make_float4(acc.x + b.x, acc.y + b.y, acc.z + b.z, acc.w + b.w);
            v.x = v.x > 0.f ? v.x : __expf(v.x) - 1.0f;
            v.y = v.y > 0.f ? v.y : __expf(v.y) - 1.0f;
            v.z = v.z > 0.f ? v.z : __expf(v.z) - 1.0f;
            v.w = v.w > 0.f ? v.w : __expf(v.w) - 1.0f;
            *(float4*)&outp[(size_t)node * HC + q * 4] = v;
        }
    } else {
        // head-mean via shuffles: lanes q<QH gather the other 3 heads' chunks
        const int qq = (q < QH) ? q : 0;
        const float x1 = __shfl(acc.x, qq + QH, 64);
        const float y1 = __shfl(acc.y, qq + QH, 64);
        const float z1 = __shfl(acc.z, qq + QH, 64);
        const float w1 = __shfl(acc.w, qq + QH, 64);
        const float x2 = __shfl(acc.x, qq + 2 * QH, 64);
        const float y2 = __shfl(acc.y, qq + 2 * QH, 64);
        const float z2 = __shfl(acc.z, qq + 2 * QH, 64);
        const float w2 = __shfl(acc.w, qq + 2 * QH, 64);
        const float x3 = __shfl(acc.x, qq + 3 * QH, 64);
        const float y3 = __shfl(acc.y, qq + 3 * QH, 64);
        const float z3 = __shfl(acc.z, qq + 3 * QH, 64);
        const float w3 = __shfl(acc.w, qq + 3 * QH, 64);
        if (q < QH && half == 0) {
            const float4 b = ((const float4*)bias)[q];
            float4 v;
            v.x = 0.25f * (acc.x + x1 + x2 + x3) + b.x;
            v.y = 0.25f * (acc.y + y1 + y2 + y3) + b.y;
            v.z = 0.25f * (acc.z + z1 + z2 + z3) + b.z;
            v.w = 0.25f * (acc.w + w1 + w2 + w3) + b.w;
            *(float4*)&outp[(size_t)node * C + q * 4] = v;
        }
    }
}

extern "C" void kernel_launch(void* const* d_in, const int* in_sizes, int n_in,
                              void* d_out, int out_size, void* d_ws, size_t ws_size,
                              hipStream_t stream) {
    const float* x      = (const float*)d_in[0];
    const int*   src    = (const int*)d_in[1];
    const int*   dst    = (const int*)d_in[2];
    const float* lin1   = (const float*)d_in[3];
    const float* att_q1 = (const float*)d_in[4];
    const float* att_v1 = (const float*)d_in[5];
    const float* bias1  = (const float*)d_in[6];
    const float* lin2   = (const float*)d_in[7];
    const float* att_q2 = (const float*)d_in[8];
    const float* att_v2 = (const float*)d_in[9];
    const float* bias2  = (const float*)d_in[10];
    float* outp = (float*)d_out;

    const int n = in_sizes[0] / 256;
    const int E = in_sizes[1];
    const int nh = n * HEADS;
    const int NB = (n + 255) / 256;

    char* wsb = (char*)d_ws;
    size_t o = 0;
    float* xh     = (float*)(wsb + o); o += (size_t)n * 160 * 4;
    float* accb   = (float*)(wsb + o); o += (size_t)n * 160 * 4;
    float* sa     = (float*)(wsb + o); o += (size_t)nh * 4;
    int* csr_src  = (int*)(wsb + o); o += (size_t)E * 4;
    int* deg      = (int*)(wsb + o); o += (size_t)n * 4;
    int* ro       = (int*)(wsb + o); o += (size_t)(n + 1) * 4;
    int* cur      = (int*)(wsb + o); o += (size_t)n * 4;
    int* bsum     = (int*)(wsb + o); o += 256 * 4;

    dim3 blk(256);
    const int EG = (E + 255) / 256;

    // ---- CSR build (dst is layer-invariant: build once, use twice) ----
    hipMemsetAsync(deg, 0, (size_t)n * 4, stream);
    hist_k<<<EG, blk, 0, stream>>>(dst, deg, E);
    scan1_k<<<NB, blk, 0, stream>>>(deg, ro, bsum, n);
    scan2_k<<<1, blk, 0, stream>>>(bsum, NB);
    scan3_k<<<NB, blk, 0, stream>>>(ro, cur, bsum, n, E);
    scatter_idx_k<<<EG, blk, 0, stream>>>(src, dst, cur, csr_src, E);

    // ================= layer 1: C=32, HC=128, K=256 =================
    gemm_k<<<dim3((n + 127) / 128, 128 / 32), blk, 0, stream>>>(x, lin1, xh, n, 256, 128);
    alpha_k<<<(nh + 255) / 256, blk, 0, stream>>>(xh, att_q1, sa, n, 32, 128);
    fused_edge_k<32, true><<<(n + 3) / 4, blk, 0, stream>>>(ro, csr_src, xh, sa, att_v1, bias1, accb, n);

    // ================= layer 2: C=40, HC=160, K=128 =================
    gemm_k<<<dim3((n + 127) / 128, 160 / 32), blk, 0, stream>>>(accb, lin2, xh, n, 128, 160);
    alpha_k<<<(nh + 255) / 256, blk, 0, stream>>>(xh, att_q2, sa, n, 40, 160);
    fused_edge_k<40, false><<<(n + 3) / 4, blk, 0, stream>>>(ro, csr_src, xh, sa, att_v2, bias2, outp, n);
}